// Round 18
// baseline (236.824 us; speedup 1.0000x reference)
//
#include <hip/hip_runtime.h>
#include <hip/hip_bf16.h>

typedef __bf16 bf16x8 __attribute__((ext_vector_type(8)));
typedef float f32x4 __attribute__((ext_vector_type(4)));
typedef unsigned int u32;

#define BATCH 65536
#define NL 256
#define NZ 1024
#define FEAT 5
#define KTOT 288   // 256 (h@U) + 32 (x@W folded)
#define AST 288    // Abig / A_sh row stride (bf16): 576B, raw-copyable
#define ROWS 32    // rows per tile
#define COLS 128   // gate-cols per block
#define SLAB_T 8   // tiles per persistent block
#define NBLK 512   // persistent blocks (2/CU)
#define CH 132     // c_buf/h_buf row stride (f32); 528B -> rotated banks
// fallback (R13) constants
#define FB_ROWS 64
#define FB_COLS 128
#define ASTRIDE 296
#define CSTR 132

__device__ __forceinline__ unsigned short f2bf(float f) {
  __hip_bfloat16 h = __float2bfloat16(f);  // RTNE
  return __builtin_bit_cast(unsigned short, h);
}
__device__ __forceinline__ float sigm(float z) {
  return __builtin_amdgcn_rcpf(1.f + __builtin_amdgcn_exp2f(z * -1.4426950408889634f));
}

#define GLOAD16(g, l)                                                              \
  __builtin_amdgcn_global_load_lds((const __attribute__((address_space(1))) u32*)(g), \
                                   (__attribute__((address_space(3))) u32*)(l), 16, 0, 0)

// ---- merged prep: [0,8192) Abig | [8192,8448) U-transpose | [8448,8576) Ut-x | [8576,8592) WdTg
__global__ __launch_bounds__(256) void k_prep_all(
    const float* __restrict__ h0, const float* __restrict__ x,
    const float* __restrict__ U, const float* __restrict__ W,
    const float* __restrict__ Wd, unsigned short* __restrict__ Abig,
    unsigned short* __restrict__ Ut, unsigned short* __restrict__ WdTg) {
  __shared__ float t[32][33];
  const int tid = threadIdx.x;
  const int bid = blockIdx.x;

  if (bid < 8192) {  // Abig[row][0..255]=bf16(h0), [256..260]=bf16(x), [261..287]=0
    const int row8 = bid * 8;
    const int r = tid >> 5;
    const int c8 = tid & 31;
    const int row = row8 + r;
    const float4 v0 = *reinterpret_cast<const float4*>(h0 + (size_t)row * NL + c8 * 8);
    const float4 v1 = *reinterpret_cast<const float4*>(h0 + (size_t)row * NL + c8 * 8 + 4);
    unsigned short* dst = Abig + (size_t)row * AST + c8 * 8;
    *reinterpret_cast<ushort4*>(dst) = make_ushort4(f2bf(v0.x), f2bf(v0.y), f2bf(v0.z), f2bf(v0.w));
    *reinterpret_cast<ushort4*>(dst + 4) = make_ushort4(f2bf(v1.x), f2bf(v1.y), f2bf(v1.z), f2bf(v1.w));
    if (tid < 32) {
      const int rr = row8 + (tid >> 2);
      const int seg = tid & 3;
      unsigned short vals[8];
#pragma unroll
      for (int e = 0; e < 8; ++e) {
        const int col = seg * 8 + e;
        vals[e] = (col < FEAT) ? f2bf(x[(size_t)rr * FEAT + col]) : (unsigned short)0;
      }
      unsigned short* d2 = Abig + (size_t)rr * AST + 256 + seg * 8;
      *reinterpret_cast<ushort4*>(d2) = make_ushort4(vals[0], vals[1], vals[2], vals[3]);
      *reinterpret_cast<ushort4*>(d2 + 4) = make_ushort4(vals[4], vals[5], vals[6], vals[7]);
    }
  } else if (bid < 8448) {  // U [256][1024] -> Ut [1024][288] rows k=0..255
    const int b2 = bid - 8192;
    const int bk = b2 >> 5;
    const int bn = b2 & 31;
    const int r = tid >> 5;
    const int c = tid & 31;
#pragma unroll
    for (int i = 0; i < 4; ++i)
      t[r + 8 * i][c] = U[(size_t)(bk * 32 + r + 8 * i) * NZ + bn * 32 + c];
    __syncthreads();
#pragma unroll
    for (int i = 0; i < 4; ++i)
      Ut[(size_t)(bn * 32 + r + 8 * i) * KTOT + bk * 32 + c] = f2bf(t[c][r + 8 * i]);
  } else if (bid < 8576) {  // Ut k-rows 256..287 = [W(5); zeros]
    const int idx = (bid - 8448) * 256 + tid;  // 32768
    const int n = idx >> 5;
    const int cc = idx & 31;
    Ut[(size_t)n * KTOT + 256 + cc] =
        (cc < FEAT) ? f2bf(W[(size_t)cc * NZ + n]) : (unsigned short)0;
  } else {  // WdTg [16][256]
    const int idx = (bid - 8576) * 256 + tid;  // 4096
    const int p = idx >> 8;
    const int j = idx & 255;
    WdTg[p * 256 + j] = (p < FEAT) ? f2bf(Wd[(size_t)j * FEAT + p]) : (unsigned short)0;
  }
}

// async stage of tile A (18 KB linear raw copy), 8 waves: 18 chunks of 1 KB
__device__ __forceinline__ void issue_tile(const unsigned short* Abig, int mt,
                                           int w, int l, unsigned short* Abuf) {
  const char* gA = (const char*)(Abig + (size_t)mt * AST);
  char* lA = (char*)Abuf;
#pragma unroll
  for (int i = 0; i < 3; ++i) {
    const int ii = w + i * 8;  // wave-uniform
    if (ii < 18) GLOAD16(gA + ii * 1024 + l * 16, lA + ii * 1024);
  }
}

// Persistent pipelined: 512 blocks x 512 thr (8 waves; 2 blocks/CU = 16 waves/CU),
// slab of 8 tiles; A dbuf via global_load_lds; c0 = 8 scattered reg-loads hoisted
// before the k-loop; c/h routed through single f32 LDS bufs for coalesced stores.
__global__ __launch_bounds__(512, 4) void k_lstm_p(
    const float* __restrict__ c0, const float* __restrict__ b,
    const float* __restrict__ bd, const unsigned short* __restrict__ Ut,
    const unsigned short* __restrict__ WdTg,
    const unsigned short* __restrict__ Abig, float* __restrict__ out) {
  float* out_logits = out;
  float* out_h = out + (size_t)BATCH * FEAT;
  float* out_c = out_h + (size_t)BATCH * NL;

  __shared__ __align__(16) unsigned short A_sh[2][ROWS * AST];  // 2 x 18432 B
  __shared__ __align__(16) float c_buf[ROWS * CH];              // 16896 B
  __shared__ __align__(16) float h_buf[ROWS * CH];              // 16896 B

  const int tid = threadIdx.x;
  const int w = tid >> 6;   // wave 0..7
  const int l = tid & 63;
  const int lrow = l & 15;
  const int lk8 = (l >> 4) * 8;
  const int lq = (l >> 4) * 4;

  // XCD-contiguous: 64 blocks/XCD = 32 slabs x 2 cg (cg-siblings co-XCD)
  const int xcd = (int)blockIdx.x & 7;
  const int gidx = xcd * 64 + ((int)blockIdx.x >> 3);  // 0..511
  const int cg = gidx & 1;
  const int slab = gidx >> 1;                          // 0..255
  const int mbase = slab * (ROWS * SLAB_T);            // 256 rows/slab

  const int jcol = cg * COLS + w * 16 + lrow;  // gate col 0..255
  const int wcol = w * 16 + lrow;              // col within block 0..127

  float bb[4];
#pragma unroll
  for (int g = 0; g < 4; ++g) bb[g] = b[g * 256 + jcol];
  const unsigned short* bp[4];
#pragma unroll
  for (int g = 0; g < 4; ++g) bp[g] = Ut + (size_t)(g * 256 + jcol) * KTOT + lk8;
  // logits role: wave w -> rows16=(w&1)*16, col-chunk kk2w=w>>1 (1 MFMA/wave)
  const int rows16 = (w & 1) * 16;
  const int kk2w = w >> 1;
  const float bdv = (cg == 0 && kk2w == 0 && lrow < FEAT) ? bd[lrow] : 0.f;

  issue_tile(Abig, mbase, w, l, &A_sh[0][0]);
  asm volatile("s_waitcnt vmcnt(0)" ::: "memory");
  __syncthreads();

  int cur = 0;
#pragma unroll 1
  for (int t = 0; t < SLAB_T; ++t) {
    const int m0 = mbase + t * ROWS;
    if (t + 1 < SLAB_T) issue_tile(Abig, m0 + ROWS, w, l, &A_sh[cur ^ 1][0]);

    // c0 reg-loads for THIS tile: latency hides under the k-loop below
    float c0v[2][4];
#pragma unroll
    for (int r = 0; r < 2; ++r)
#pragma unroll
      for (int v = 0; v < 4; ++v)
        c0v[r][v] = c0[(size_t)(m0 + r * 16 + lq + v) * NL + jcol];

    // ---- k-loop on A_sh[cur]: B reg-rotation (2-deep), setprio on MFMA
    f32x4 acc[2][4];
#pragma unroll
    for (int r = 0; r < 2; ++r)
#pragma unroll
      for (int g = 0; g < 4; ++g) acc[r][g] = (f32x4){0.f, 0.f, 0.f, 0.f};
    const unsigned short* Ab = &A_sh[cur][0];

    bf16x8 bbuf[3][4];
#pragma unroll
    for (int g = 0; g < 4; ++g) bbuf[0][g] = *reinterpret_cast<const bf16x8*>(bp[g]);
#pragma unroll
    for (int g = 0; g < 4; ++g) bbuf[1][g] = *reinterpret_cast<const bf16x8*>(bp[g] + 32);

#pragma unroll
    for (int kk = 0; kk < 9; ++kk) {
      if (kk < 7) {
#pragma unroll
        for (int g = 0; g < 4; ++g)
          bbuf[(kk + 2) % 3][g] = *reinterpret_cast<const bf16x8*>(bp[g] + (kk + 2) * 32);
        __builtin_amdgcn_sched_group_barrier(0x20, 4, 0);  // VMEM_READ x4 first
      }
      const bf16x8 af0 = *reinterpret_cast<const bf16x8*>(&Ab[lrow * AST + kk * 32 + lk8]);
      const bf16x8 af1 =
          *reinterpret_cast<const bf16x8*>(&Ab[(16 + lrow) * AST + kk * 32 + lk8]);
      __builtin_amdgcn_sched_group_barrier(0x100, 2, 0);   // DS_READ x2
      __builtin_amdgcn_s_setprio(1);
#pragma unroll
      for (int g = 0; g < 4; ++g) {
        acc[0][g] = __builtin_amdgcn_mfma_f32_16x16x32_bf16(af0, bbuf[kk % 3][g], acc[0][g], 0, 0, 0);
        acc[1][g] = __builtin_amdgcn_mfma_f32_16x16x32_bf16(af1, bbuf[kk % 3][g], acc[1][g], 0, 0, 0);
      }
      __builtin_amdgcn_s_setprio(0);
      __builtin_amdgcn_sched_group_barrier(0x8, 8, 0);     // MFMA x8
    }

    // ---- gates: results into c_buf/h_buf (scattered f32 LDS writes)
#pragma unroll
    for (int r = 0; r < 2; ++r) {
#pragma unroll
      for (int v = 0; v < 4; ++v) {
        const int mloc = r * 16 + lq + v;
        const float zi = acc[r][0][v] + bb[0];
        const float zf = acc[r][1][v] + bb[1];
        const float zc = acc[r][2][v] + bb[2];
        const float zo = acc[r][3][v] + bb[3];
        const float ig = sigm(zi);
        const float fg = sigm(zf);
        const float og = sigm(zo);
        const float rc = fmaxf(zc, 0.f);
        const float cv = fg * c0v[r][v] + ig * rc;
        const float hv = og * fmaxf(cv, 0.f);
        c_buf[mloc * CH + wcol] = cv;
        h_buf[mloc * CH + wcol] = hv;
      }
    }
    __syncthreads();  // B1: k-loop A_sh[cur] reads done; c/h visible

    // ---- coalesced h & c stores (2 float4/thread each): 32 rows x 32 float4
#pragma unroll
    for (int it = 0; it < 2; ++it) {
      const int fi = it * 512 + tid;  // 1024 float4
      const int row = fi >> 5, c4 = fi & 31;
      const float4 hv4 = *reinterpret_cast<const float4*>(&h_buf[row * CH + c4 * 4]);
      *reinterpret_cast<float4*>(out_h + (size_t)(m0 + row) * NL + cg * COLS + c4 * 4) = hv4;
      const float4 cv4 = *reinterpret_cast<const float4*>(&c_buf[row * CH + c4 * 4]);
      *reinterpret_cast<float4*>(out_c + (size_t)(m0 + row) * NL + cg * COLS + c4 * 4) = cv4;
    }
    // ---- logits: 1 MFMA per wave (8 units = 2 rowgroups x 4 col-chunks)
    {
      const float4 hlo = *reinterpret_cast<const float4*>(
          &h_buf[(rows16 + lrow) * CH + kk2w * 32 + lk8]);
      const float4 hhi = *reinterpret_cast<const float4*>(
          &h_buf[(rows16 + lrow) * CH + kk2w * 32 + lk8 + 4]);
      bf16x8 ah;
      ah[0] = (__bf16)hlo.x; ah[1] = (__bf16)hlo.y;
      ah[2] = (__bf16)hlo.z; ah[3] = (__bf16)hlo.w;
      ah[4] = (__bf16)hhi.x; ah[5] = (__bf16)hhi.y;
      ah[6] = (__bf16)hhi.z; ah[7] = (__bf16)hhi.w;
      const bf16x8 bw = *reinterpret_cast<const bf16x8*>(
          &WdTg[lrow * 256 + cg * COLS + kk2w * 32 + lk8]);
      f32x4 lacc = (f32x4){0.f, 0.f, 0.f, 0.f};
      lacc = __builtin_amdgcn_mfma_f32_16x16x32_bf16(ah, bw, lacc, 0, 0, 0);
      if (lrow < FEAT) {
#pragma unroll
        for (int v = 0; v < 4; ++v)
          atomicAdd(&out_logits[(size_t)(m0 + rows16 + lq + v) * FEAT + lrow],
                    lacc[v] + bdv);
      }
    }
    // counted drain: staging gloads retired once <=8 VM ops remain (c0 loads,
    // 36 B loads, stores, atomics all issued after them); stores stay in flight.
    asm volatile("s_waitcnt vmcnt(8)" ::: "memory");
    __syncthreads();  // B2
    cur ^= 1;
  }
}

// ---------------- fallback (ws too small): R13 kernel + split preps ----------------
__global__ __launch_bounds__(256) void k_prep_fb(const float* __restrict__ U,
                                                 unsigned short* __restrict__ Ut) {
  __shared__ float t[32][33];
  const int bk = blockIdx.x >> 5;
  const int bn = blockIdx.x & 31;
  const int r = threadIdx.x >> 5;
  const int c = threadIdx.x & 31;
#pragma unroll
  for (int i = 0; i < 4; ++i)
    t[r + 8 * i][c] = U[(size_t)(bk * 32 + r + 8 * i) * NZ + bn * 32 + c];
  __syncthreads();
#pragma unroll
  for (int i = 0; i < 4; ++i)
    Ut[(size_t)(bn * 32 + r + 8 * i) * KTOT + bk * 32 + c] = f2bf(t[c][r + 8 * i]);
}
__global__ __launch_bounds__(1024) void k_prepx_fb(const float* __restrict__ W,
                                                   const float* __restrict__ Wd,
                                                   unsigned short* __restrict__ Ut,
                                                   unsigned short* __restrict__ WdTg) {
  const int idx = blockIdx.x * 1024 + threadIdx.x;
  const int n = idx >> 5;
  const int cc = idx & 31;
  Ut[(size_t)n * KTOT + 256 + cc] = (cc < FEAT) ? f2bf(W[(size_t)cc * NZ + n]) : (unsigned short)0;
  if (blockIdx.x < 4) {
    const int p = idx >> 8;
    const int j = idx & 255;
    WdTg[p * 256 + j] = (p < FEAT) ? f2bf(Wd[(size_t)j * FEAT + p]) : (unsigned short)0;
  }
}
__global__ __launch_bounds__(512, 4) void k_lstm_fb(
    const float* __restrict__ x, const float* __restrict__ h0,
    const float* __restrict__ c0, const float* __restrict__ b,
    const float* __restrict__ bd, const unsigned short* __restrict__ Ut,
    const unsigned short* __restrict__ WdTg, float* __restrict__ out) {
  float* out_logits = out;
  float* out_h = out + (size_t)BATCH * FEAT;
  float* out_c = out_h + (size_t)BATCH * NL;
  __shared__ __align__(16) unsigned short A_sh[FB_ROWS * ASTRIDE];
  __shared__ __align__(16) float c0_sh[FB_ROWS * CSTR];
  const int tid = threadIdx.x;
  const int w = tid >> 6;
  const int l = tid & 63;
  const int lrow = l & 15;
  const int lk8 = (l >> 4) * 8;
  const int lq = (l >> 4) * 4;
  const int nb = ((int)blockIdx.x & 7) * 256 + ((int)blockIdx.x >> 3);
  const int cg = nb & 1;
  const int m0 = (nb >> 1) * FB_ROWS;
  const int jcol = cg * FB_COLS + w * 16 + lrow;
  const int wcol = w * 16 + lrow;
  {
    float4 sv[8];
#pragma unroll
    for (int it = 0; it < 8; ++it) {
      const int fi = it * 512 + tid;
      const int row = fi >> 6, c4 = fi & 63;
      sv[it] = *reinterpret_cast<const float4*>(h0 + (size_t)(m0 + row) * NL + c4 * 4);
    }
#pragma unroll
    for (int it = 0; it < 8; ++it) {
      const int fi = it * 512 + tid;
      const int row = fi >> 6, c4 = fi & 63;
      *reinterpret_cast<ushort4*>(&A_sh[row * ASTRIDE + c4 * 4]) =
          make_ushort4(f2bf(sv[it].x), f2bf(sv[it].y), f2bf(sv[it].z), f2bf(sv[it].w));
    }
  }
  {
    float4 cv[4];
#pragma unroll
    for (int it = 0; it < 4; ++it) {
      const int fi = it * 512 + tid;
      const int row = fi >> 5, c4 = fi & 31;
      cv[it] = *reinterpret_cast<const float4*>(c0 + (size_t)(m0 + row) * NL + cg * FB_COLS + c4 * 4);
    }
#pragma unroll
    for (int it = 0; it < 4; ++it) {
      const int fi = it * 512 + tid;
      const int row = fi >> 5, c4 = fi & 31;
      *reinterpret_cast<float4*>(&c0_sh[row * CSTR + c4 * 4]) = cv[it];
    }
  }
#pragma unroll
  for (int it = 0; it < 4; ++it) {
    const int idx = it * 512 + tid;
    const int row = idx >> 5, cc = idx & 31;
    const float xv = (cc < FEAT) ? x[(size_t)(m0 + row) * FEAT + cc] : 0.f;
    A_sh[row * ASTRIDE + 256 + cc] = f2bf(xv);
  }
  __syncthreads();
  float bb[4];
#pragma unroll
  for (int g = 0; g < 4; ++g) bb[g] = b[g * 256 + jcol];
  f32x4 acc[4][4];
#pragma unroll
  for (int r = 0; r < 4; ++r)
#pragma unroll
    for (int g = 0; g < 4; ++g) acc[r][g] = (f32x4){0.f, 0.f, 0.f, 0.f};
  const unsigned short* bp[4];
#pragma unroll
  for (int g = 0; g < 4; ++g) bp[g] = Ut + (size_t)(g * 256 + jcol) * KTOT + lk8;
#pragma unroll
  for (int kk = 0; kk < 9; ++kk) {
    bf16x8 bf[4];
#pragma unroll
    for (int g = 0; g < 4; ++g) bf[g] = *reinterpret_cast<const bf16x8*>(bp[g] + kk * 32);
    bf16x8 af[4];
#pragma unroll
    for (int r = 0; r < 4; ++r)
      af[r] = *reinterpret_cast<const bf16x8*>(&A_sh[(r * 16 + lrow) * ASTRIDE + kk * 32 + lk8]);
#pragma unroll
    for (int g = 0; g < 4; ++g)
#pragma unroll
      for (int r = 0; r < 4; ++r)
        acc[r][g] = __builtin_amdgcn_mfma_f32_16x16x32_bf16(af[r], bf[g], acc[r][g], 0, 0, 0);
  }
  __syncthreads();
  float* t_sh = reinterpret_cast<float*>(A_sh);
#pragma unroll
  for (int r = 0; r < 4; ++r) {
#pragma unroll
    for (int v = 0; v < 4; ++v) {
      const int mloc = r * 16 + lq + v;
      const float zi = acc[r][0][v] + bb[0];
      const float zf = acc[r][1][v] + bb[1];
      const float zc = acc[r][2][v] + bb[2];
      const float zo = acc[r][3][v] + bb[3];
      const float ig = sigm(zi);
      const float fg = sigm(zf);
      const float og = sigm(zo);
      const float rc = fmaxf(zc, 0.f);
      const float cv = fg * c0_sh[mloc * CSTR + wcol] + ig * rc;
      const float hv = og * fmaxf(cv, 0.f);
      c0_sh[mloc * CSTR + wcol] = cv;
      t_sh[mloc * CSTR + wcol] = hv;
    }
  }
  __syncthreads();
#pragma unroll
  for (int it = 0; it < 4; ++it) {
    const int fi = it * 512 + tid;
    const int row = fi >> 5, c4 = fi & 31;
    const float4 hv4 = *reinterpret_cast<const float4*>(&t_sh[row * CSTR + c4 * 4]);
    *reinterpret_cast<float4*>(out_h + (size_t)(m0 + row) * NL + cg * FB_COLS + c4 * 4) = hv4;
    const float4 cv4 = *reinterpret_cast<const float4*>(&c0_sh[row * CSTR + c4 * 4]);
    *reinterpret_cast<float4*>(out_c + (size_t)(m0 + row) * NL + cg * FB_COLS + c4 * 4) = cv4;
  }
  if (w < 4) {
    f32x4 lacc = (f32x4){0.f, 0.f, 0.f, 0.f};
#pragma unroll
    for (int kk2 = 0; kk2 < 4; ++kk2) {
      const float4 hlo = *reinterpret_cast<const float4*>(&t_sh[(w * 16 + lrow) * CSTR + kk2 * 32 + lk8]);
      const float4 hhi = *reinterpret_cast<const float4*>(&t_sh[(w * 16 + lrow) * CSTR + kk2 * 32 + lk8 + 4]);
      bf16x8 ah;
      ah[0] = (__bf16)hlo.x; ah[1] = (__bf16)hlo.y;
      ah[2] = (__bf16)hlo.z; ah[3] = (__bf16)hlo.w;
      ah[4] = (__bf16)hhi.x; ah[5] = (__bf16)hhi.y;
      ah[6] = (__bf16)hhi.z; ah[7] = (__bf16)hhi.w;
      const bf16x8 bw = *reinterpret_cast<const bf16x8*>(&WdTg[lrow * 256 + cg * FB_COLS + kk2 * 32 + lk8]);
      lacc = __builtin_amdgcn_mfma_f32_16x16x32_bf16(ah, bw, lacc, 0, 0, 0);
    }
    if (lrow < FEAT) {
      const float addv = (cg == 0) ? bd[lrow] : 0.f;
#pragma unroll
      for (int v = 0; v < 4; ++v)
        atomicAdd(&out_logits[(size_t)(m0 + w * 16 + lq + v) * FEAT + lrow], lacc[v] + addv);
    }
  }
}

extern "C" void kernel_launch(void* const* d_in, const int* in_sizes, int n_in,
                              void* d_out, int out_size, void* d_ws, size_t ws_size,
                              hipStream_t stream) {
  const float* x = (const float*)d_in[0];
  const float* h0 = (const float*)d_in[1];
  const float* c0 = (const float*)d_in[2];
  const float* W = (const float*)d_in[3];
  const float* U = (const float*)d_in[4];
  const float* b = (const float*)d_in[5];
  const float* Wd = (const float*)d_in[6];
  const float* bd = (const float*)d_in[7];

  unsigned short* Ut = (unsigned short*)d_ws;            // 589824 B
  unsigned short* WdTg = Ut + (size_t)NZ * KTOT;         // +8192 B
  unsigned short* Abig = WdTg + 16 * 256;                // +37748736 B
  const size_t need = (size_t)NZ * KTOT * 2 + 16 * 256 * 2 + (size_t)BATCH * AST * 2;

  hipMemsetAsync(d_out, 0, (size_t)BATCH * FEAT * sizeof(float), stream);

  if (ws_size >= need) {
    k_prep_all<<<8592, 256, 0, stream>>>(h0, x, U, W, Wd, Abig, Ut, WdTg);
    k_lstm_p<<<NBLK, 512, 0, stream>>>(c0, b, bd, Ut, WdTg, Abig, (float*)d_out);
  } else {
    k_prep_fb<<<256, 256, 0, stream>>>(U, Ut);
    k_prepx_fb<<<32, 1024, 0, stream>>>(W, Wd, Ut, WdTg);
    k_lstm_fb<<<(BATCH / FB_ROWS) * 2, 512, 0, stream>>>(x, h0, c0, b, bd, Ut, WdTg,
                                                         (float*)d_out);
  }
}

// Round 19
// 118.184 us; speedup vs baseline: 2.0039x; 2.0039x over previous
//
#include <hip/hip_runtime.h>
#include <hip/hip_bf16.h>

typedef __bf16 bf16x8 __attribute__((ext_vector_type(8)));
typedef float f32x4 __attribute__((ext_vector_type(4)));
typedef unsigned int u32;

#define BATCH 65536
#define NL 256
#define NZ 1024
#define FEAT 5
#define KTOT 288   // 256 (h@U) + 32 (x@W folded)
#define AST 288    // Abig / A_sh row stride (bf16): 576B, raw-copyable
#define ROWS 32    // rows per tile
#define COLS 128   // gate-cols per block
#define SLAB_T 8   // tiles per persistent block
#define NBLK 512   // persistent blocks (2/CU)
#define CH 132     // c_buf/h_buf row stride (f32); 528B -> rotated banks
// fallback (R13) constants
#define FB_ROWS 64
#define FB_COLS 128
#define ASTRIDE 296
#define CSTR 132

__device__ __forceinline__ unsigned short f2bf(float f) {
  __hip_bfloat16 h = __float2bfloat16(f);  // RTNE
  return __builtin_bit_cast(unsigned short, h);
}
__device__ __forceinline__ float sigm(float z) {
  return __builtin_amdgcn_rcpf(1.f + __builtin_amdgcn_exp2f(z * -1.4426950408889634f));
}

#define GLOAD16(g, l)                                                              \
  __builtin_amdgcn_global_load_lds((const __attribute__((address_space(1))) u32*)(g), \
                                   (__attribute__((address_space(3))) u32*)(l), 16, 0, 0)

// ---- merged prep: [0,8192) Abig | [8192,8448) U-transpose | [8448,8576) Ut-x | [8576,8592) WdTg
__global__ __launch_bounds__(256) void k_prep_all(
    const float* __restrict__ h0, const float* __restrict__ x,
    const float* __restrict__ U, const float* __restrict__ W,
    const float* __restrict__ Wd, unsigned short* __restrict__ Abig,
    unsigned short* __restrict__ Ut, unsigned short* __restrict__ WdTg) {
  __shared__ float t[32][33];
  const int tid = threadIdx.x;
  const int bid = blockIdx.x;

  if (bid < 8192) {  // Abig[row][0..255]=bf16(h0), [256..260]=bf16(x), [261..287]=0
    const int row8 = bid * 8;
    const int r = tid >> 5;
    const int c8 = tid & 31;
    const int row = row8 + r;
    const float4 v0 = *reinterpret_cast<const float4*>(h0 + (size_t)row * NL + c8 * 8);
    const float4 v1 = *reinterpret_cast<const float4*>(h0 + (size_t)row * NL + c8 * 8 + 4);
    unsigned short* dst = Abig + (size_t)row * AST + c8 * 8;
    *reinterpret_cast<ushort4*>(dst) = make_ushort4(f2bf(v0.x), f2bf(v0.y), f2bf(v0.z), f2bf(v0.w));
    *reinterpret_cast<ushort4*>(dst + 4) = make_ushort4(f2bf(v1.x), f2bf(v1.y), f2bf(v1.z), f2bf(v1.w));
    if (tid < 32) {
      const int rr = row8 + (tid >> 2);
      const int seg = tid & 3;
      unsigned short vals[8];
#pragma unroll
      for (int e = 0; e < 8; ++e) {
        const int col = seg * 8 + e;
        vals[e] = (col < FEAT) ? f2bf(x[(size_t)rr * FEAT + col]) : (unsigned short)0;
      }
      unsigned short* d2 = Abig + (size_t)rr * AST + 256 + seg * 8;
      *reinterpret_cast<ushort4*>(d2) = make_ushort4(vals[0], vals[1], vals[2], vals[3]);
      *reinterpret_cast<ushort4*>(d2 + 4) = make_ushort4(vals[4], vals[5], vals[6], vals[7]);
    }
  } else if (bid < 8448) {  // U [256][1024] -> Ut [1024][288] rows k=0..255
    const int b2 = bid - 8192;
    const int bk = b2 >> 5;
    const int bn = b2 & 31;
    const int r = tid >> 5;
    const int c = tid & 31;
#pragma unroll
    for (int i = 0; i < 4; ++i)
      t[r + 8 * i][c] = U[(size_t)(bk * 32 + r + 8 * i) * NZ + bn * 32 + c];
    __syncthreads();
#pragma unroll
    for (int i = 0; i < 4; ++i)
      Ut[(size_t)(bn * 32 + r + 8 * i) * KTOT + bk * 32 + c] = f2bf(t[c][r + 8 * i]);
  } else if (bid < 8576) {  // Ut k-rows 256..287 = [W(5); zeros]
    const int idx = (bid - 8448) * 256 + tid;  // 32768
    const int n = idx >> 5;
    const int cc = idx & 31;
    Ut[(size_t)n * KTOT + 256 + cc] =
        (cc < FEAT) ? f2bf(W[(size_t)cc * NZ + n]) : (unsigned short)0;
  } else {  // WdTg [16][256]
    const int idx = (bid - 8576) * 256 + tid;  // 4096
    const int p = idx >> 8;
    const int j = idx & 255;
    WdTg[p * 256 + j] = (p < FEAT) ? f2bf(Wd[(size_t)j * FEAT + p]) : (unsigned short)0;
  }
}

// async stage of tile A (18 KB linear raw copy), 8 waves: 18 chunks of 1 KB
__device__ __forceinline__ void issue_tile(const unsigned short* Abig, int mt,
                                           int w, int l, unsigned short* Abuf) {
  const char* gA = (const char*)(Abig + (size_t)mt * AST);
  char* lA = (char*)Abuf;
#pragma unroll
  for (int i = 0; i < 3; ++i) {
    const int ii = w + i * 8;  // wave-uniform
    if (ii < 18) GLOAD16(gA + ii * 1024 + l * 16, lA + ii * 1024);
  }
}

// Persistent pipelined: 512 blocks x 512 thr (8 waves; 2 blocks/CU = 16 waves/CU),
// slab of 8 tiles; A dbuf via global_load_lds; c0 = 8 scattered reg-loads hoisted
// before the k-loop; c/h routed through single f32 LDS bufs for coalesced stores.
// launch_bounds(512,2): 256-reg budget so the B reg-rotation is NOT spilled
// (R18's (512,4) forced 128 regs -> scratch spill, FETCH+457MB).
__global__ __launch_bounds__(512, 2) void k_lstm_p(
    const float* __restrict__ c0, const float* __restrict__ b,
    const float* __restrict__ bd, const unsigned short* __restrict__ Ut,
    const unsigned short* __restrict__ WdTg,
    const unsigned short* __restrict__ Abig, float* __restrict__ out) {
  float* out_logits = out;
  float* out_h = out + (size_t)BATCH * FEAT;
  float* out_c = out_h + (size_t)BATCH * NL;

  __shared__ __align__(16) unsigned short A_sh[2][ROWS * AST];  // 2 x 18432 B
  __shared__ __align__(16) float c_buf[ROWS * CH];              // 16896 B
  __shared__ __align__(16) float h_buf[ROWS * CH];              // 16896 B

  const int tid = threadIdx.x;
  const int w = tid >> 6;   // wave 0..7
  const int l = tid & 63;
  const int lrow = l & 15;
  const int lk8 = (l >> 4) * 8;
  const int lq = (l >> 4) * 4;

  // XCD-contiguous: 64 blocks/XCD = 32 slabs x 2 cg (cg-siblings co-XCD)
  const int xcd = (int)blockIdx.x & 7;
  const int gidx = xcd * 64 + ((int)blockIdx.x >> 3);  // 0..511
  const int cg = gidx & 1;
  const int slab = gidx >> 1;                          // 0..255
  const int mbase = slab * (ROWS * SLAB_T);            // 256 rows/slab

  const int jcol = cg * COLS + w * 16 + lrow;  // gate col 0..255
  const int wcol = w * 16 + lrow;              // col within block 0..127

  float bb[4];
#pragma unroll
  for (int g = 0; g < 4; ++g) bb[g] = b[g * 256 + jcol];
  const unsigned short* bp[4];
#pragma unroll
  for (int g = 0; g < 4; ++g) bp[g] = Ut + (size_t)(g * 256 + jcol) * KTOT + lk8;
  // logits role: wave w -> rows16=(w&1)*16, col-chunk kk2w=w>>1 (1 MFMA/wave)
  const int rows16 = (w & 1) * 16;
  const int kk2w = w >> 1;
  const float bdv = (cg == 0 && kk2w == 0 && lrow < FEAT) ? bd[lrow] : 0.f;

  issue_tile(Abig, mbase, w, l, &A_sh[0][0]);
  asm volatile("s_waitcnt vmcnt(0)" ::: "memory");
  __syncthreads();

  int cur = 0;
#pragma unroll 1
  for (int t = 0; t < SLAB_T; ++t) {
    const int m0 = mbase + t * ROWS;
    if (t + 1 < SLAB_T) issue_tile(Abig, m0 + ROWS, w, l, &A_sh[cur ^ 1][0]);

    // c0 reg-loads for THIS tile: latency hides under the k-loop below
    float c0v[2][4];
#pragma unroll
    for (int r = 0; r < 2; ++r)
#pragma unroll
      for (int v = 0; v < 4; ++v)
        c0v[r][v] = c0[(size_t)(m0 + r * 16 + lq + v) * NL + jcol];

    // ---- k-loop on A_sh[cur]: B reg-rotation (2-deep), setprio on MFMA
    f32x4 acc[2][4];
#pragma unroll
    for (int r = 0; r < 2; ++r)
#pragma unroll
      for (int g = 0; g < 4; ++g) acc[r][g] = (f32x4){0.f, 0.f, 0.f, 0.f};
    const unsigned short* Ab = &A_sh[cur][0];

    bf16x8 bbuf[3][4];
#pragma unroll
    for (int g = 0; g < 4; ++g) bbuf[0][g] = *reinterpret_cast<const bf16x8*>(bp[g]);
#pragma unroll
    for (int g = 0; g < 4; ++g) bbuf[1][g] = *reinterpret_cast<const bf16x8*>(bp[g] + 32);

#pragma unroll
    for (int kk = 0; kk < 9; ++kk) {
      if (kk < 7) {
#pragma unroll
        for (int g = 0; g < 4; ++g)
          bbuf[(kk + 2) % 3][g] = *reinterpret_cast<const bf16x8*>(bp[g] + (kk + 2) * 32);
        __builtin_amdgcn_sched_group_barrier(0x20, 4, 0);  // VMEM_READ x4 first
      }
      const bf16x8 af0 = *reinterpret_cast<const bf16x8*>(&Ab[lrow * AST + kk * 32 + lk8]);
      const bf16x8 af1 =
          *reinterpret_cast<const bf16x8*>(&Ab[(16 + lrow) * AST + kk * 32 + lk8]);
      __builtin_amdgcn_sched_group_barrier(0x100, 2, 0);   // DS_READ x2
      __builtin_amdgcn_s_setprio(1);
#pragma unroll
      for (int g = 0; g < 4; ++g) {
        acc[0][g] = __builtin_amdgcn_mfma_f32_16x16x32_bf16(af0, bbuf[kk % 3][g], acc[0][g], 0, 0, 0);
        acc[1][g] = __builtin_amdgcn_mfma_f32_16x16x32_bf16(af1, bbuf[kk % 3][g], acc[1][g], 0, 0, 0);
      }
      __builtin_amdgcn_s_setprio(0);
      __builtin_amdgcn_sched_group_barrier(0x8, 8, 0);     // MFMA x8
    }

    // ---- gates: results into c_buf/h_buf (scattered f32 LDS writes)
#pragma unroll
    for (int r = 0; r < 2; ++r) {
#pragma unroll
      for (int v = 0; v < 4; ++v) {
        const int mloc = r * 16 + lq + v;
        const float zi = acc[r][0][v] + bb[0];
        const float zf = acc[r][1][v] + bb[1];
        const float zc = acc[r][2][v] + bb[2];
        const float zo = acc[r][3][v] + bb[3];
        const float ig = sigm(zi);
        const float fg = sigm(zf);
        const float og = sigm(zo);
        const float rc = fmaxf(zc, 0.f);
        const float cv = fg * c0v[r][v] + ig * rc;
        const float hv = og * fmaxf(cv, 0.f);
        c_buf[mloc * CH + wcol] = cv;
        h_buf[mloc * CH + wcol] = hv;
      }
    }
    __syncthreads();  // B1: k-loop A_sh[cur] reads done; c/h visible

    // ---- coalesced h & c stores (2 float4/thread each): 32 rows x 32 float4
#pragma unroll
    for (int it = 0; it < 2; ++it) {
      const int fi = it * 512 + tid;  // 1024 float4
      const int row = fi >> 5, c4 = fi & 31;
      const float4 hv4 = *reinterpret_cast<const float4*>(&h_buf[row * CH + c4 * 4]);
      *reinterpret_cast<float4*>(out_h + (size_t)(m0 + row) * NL + cg * COLS + c4 * 4) = hv4;
      const float4 cv4 = *reinterpret_cast<const float4*>(&c_buf[row * CH + c4 * 4]);
      *reinterpret_cast<float4*>(out_c + (size_t)(m0 + row) * NL + cg * COLS + c4 * 4) = cv4;
    }
    // ---- logits: 1 MFMA per wave (8 units = 2 rowgroups x 4 col-chunks)
    {
      const float4 hlo = *reinterpret_cast<const float4*>(
          &h_buf[(rows16 + lrow) * CH + kk2w * 32 + lk8]);
      const float4 hhi = *reinterpret_cast<const float4*>(
          &h_buf[(rows16 + lrow) * CH + kk2w * 32 + lk8 + 4]);
      bf16x8 ah;
      ah[0] = (__bf16)hlo.x; ah[1] = (__bf16)hlo.y;
      ah[2] = (__bf16)hlo.z; ah[3] = (__bf16)hlo.w;
      ah[4] = (__bf16)hhi.x; ah[5] = (__bf16)hhi.y;
      ah[6] = (__bf16)hhi.z; ah[7] = (__bf16)hhi.w;
      const bf16x8 bw = *reinterpret_cast<const bf16x8*>(
          &WdTg[lrow * 256 + cg * COLS + kk2w * 32 + lk8]);
      f32x4 lacc = (f32x4){0.f, 0.f, 0.f, 0.f};
      lacc = __builtin_amdgcn_mfma_f32_16x16x32_bf16(ah, bw, lacc, 0, 0, 0);
      if (lrow < FEAT) {
#pragma unroll
        for (int v = 0; v < 4; ++v)
          atomicAdd(&out_logits[(size_t)(m0 + rows16 + lq + v) * FEAT + lrow],
                    lacc[v] + bdv);
      }
    }
    // counted drain: staging gloads retired once <=8 VM ops remain (c0 loads,
    // 36 B loads, stores, atomics all issued after them); stores stay in flight.
    asm volatile("s_waitcnt vmcnt(8)" ::: "memory");
    __syncthreads();  // B2
    cur ^= 1;
  }
}

// ---------------- fallback (ws too small): R13 kernel + split preps ----------------
__global__ __launch_bounds__(256) void k_prep_fb(const float* __restrict__ U,
                                                 unsigned short* __restrict__ Ut) {
  __shared__ float t[32][33];
  const int bk = blockIdx.x >> 5;
  const int bn = blockIdx.x & 31;
  const int r = threadIdx.x >> 5;
  const int c = threadIdx.x & 31;
#pragma unroll
  for (int i = 0; i < 4; ++i)
    t[r + 8 * i][c] = U[(size_t)(bk * 32 + r + 8 * i) * NZ + bn * 32 + c];
  __syncthreads();
#pragma unroll
  for (int i = 0; i < 4; ++i)
    Ut[(size_t)(bn * 32 + r + 8 * i) * KTOT + bk * 32 + c] = f2bf(t[c][r + 8 * i]);
}
__global__ __launch_bounds__(1024) void k_prepx_fb(const float* __restrict__ W,
                                                   const float* __restrict__ Wd,
                                                   unsigned short* __restrict__ Ut,
                                                   unsigned short* __restrict__ WdTg) {
  const int idx = blockIdx.x * 1024 + threadIdx.x;
  const int n = idx >> 5;
  const int cc = idx & 31;
  Ut[(size_t)n * KTOT + 256 + cc] = (cc < FEAT) ? f2bf(W[(size_t)cc * NZ + n]) : (unsigned short)0;
  if (blockIdx.x < 4) {
    const int p = idx >> 8;
    const int j = idx & 255;
    WdTg[p * 256 + j] = (p < FEAT) ? f2bf(Wd[(size_t)j * FEAT + p]) : (unsigned short)0;
  }
}
__global__ __launch_bounds__(512, 4) void k_lstm_fb(
    const float* __restrict__ x, const float* __restrict__ h0,
    const float* __restrict__ c0, const float* __restrict__ b,
    const float* __restrict__ bd, const unsigned short* __restrict__ Ut,
    const unsigned short* __restrict__ WdTg, float* __restrict__ out) {
  float* out_logits = out;
  float* out_h = out + (size_t)BATCH * FEAT;
  float* out_c = out_h + (size_t)BATCH * NL;
  __shared__ __align__(16) unsigned short A_sh[FB_ROWS * ASTRIDE];
  __shared__ __align__(16) float c0_sh[FB_ROWS * CSTR];
  const int tid = threadIdx.x;
  const int w = tid >> 6;
  const int l = tid & 63;
  const int lrow = l & 15;
  const int lk8 = (l >> 4) * 8;
  const int lq = (l >> 4) * 4;
  const int nb = ((int)blockIdx.x & 7) * 256 + ((int)blockIdx.x >> 3);
  const int cg = nb & 1;
  const int m0 = (nb >> 1) * FB_ROWS;
  const int jcol = cg * FB_COLS + w * 16 + lrow;
  const int wcol = w * 16 + lrow;
  {
    float4 sv[8];
#pragma unroll
    for (int it = 0; it < 8; ++it) {
      const int fi = it * 512 + tid;
      const int row = fi >> 6, c4 = fi & 63;
      sv[it] = *reinterpret_cast<const float4*>(h0 + (size_t)(m0 + row) * NL + c4 * 4);
    }
#pragma unroll
    for (int it = 0; it < 8; ++it) {
      const int fi = it * 512 + tid;
      const int row = fi >> 6, c4 = fi & 63;
      *reinterpret_cast<ushort4*>(&A_sh[row * ASTRIDE + c4 * 4]) =
          make_ushort4(f2bf(sv[it].x), f2bf(sv[it].y), f2bf(sv[it].z), f2bf(sv[it].w));
    }
  }
  {
    float4 cv[4];
#pragma unroll
    for (int it = 0; it < 4; ++it) {
      const int fi = it * 512 + tid;
      const int row = fi >> 5, c4 = fi & 31;
      cv[it] = *reinterpret_cast<const float4*>(c0 + (size_t)(m0 + row) * NL + cg * FB_COLS + c4 * 4);
    }
#pragma unroll
    for (int it = 0; it < 4; ++it) {
      const int fi = it * 512 + tid;
      const int row = fi >> 5, c4 = fi & 31;
      *reinterpret_cast<float4*>(&c0_sh[row * CSTR + c4 * 4]) = cv[it];
    }
  }
#pragma unroll
  for (int it = 0; it < 4; ++it) {
    const int idx = it * 512 + tid;
    const int row = idx >> 5, cc = idx & 31;
    const float xv = (cc < FEAT) ? x[(size_t)(m0 + row) * FEAT + cc] : 0.f;
    A_sh[row * ASTRIDE + 256 + cc] = f2bf(xv);
  }
  __syncthreads();
  float bb[4];
#pragma unroll
  for (int g = 0; g < 4; ++g) bb[g] = b[g * 256 + jcol];
  f32x4 acc[4][4];
#pragma unroll
  for (int r = 0; r < 4; ++r)
#pragma unroll
    for (int g = 0; g < 4; ++g) acc[r][g] = (f32x4){0.f, 0.f, 0.f, 0.f};
  const unsigned short* bp[4];
#pragma unroll
  for (int g = 0; g < 4; ++g) bp[g] = Ut + (size_t)(g * 256 + jcol) * KTOT + lk8;
#pragma unroll
  for (int kk = 0; kk < 9; ++kk) {
    bf16x8 bf[4];
#pragma unroll
    for (int g = 0; g < 4; ++g) bf[g] = *reinterpret_cast<const bf16x8*>(bp[g] + kk * 32);
    bf16x8 af[4];
#pragma unroll
    for (int r = 0; r < 4; ++r)
      af[r] = *reinterpret_cast<const bf16x8*>(&A_sh[(r * 16 + lrow) * ASTRIDE + kk * 32 + lk8]);
#pragma unroll
    for (int g = 0; g < 4; ++g)
#pragma unroll
      for (int r = 0; r < 4; ++r)
        acc[r][g] = __builtin_amdgcn_mfma_f32_16x16x32_bf16(af[r], bf[g], acc[r][g], 0, 0, 0);
  }
  __syncthreads();
  float* t_sh = reinterpret_cast<float*>(A_sh);
#pragma unroll
  for (int r = 0; r < 4; ++r) {
#pragma unroll
    for (int v = 0; v < 4; ++v) {
      const int mloc = r * 16 + lq + v;
      const float zi = acc[r][0][v] + bb[0];
      const float zf = acc[r][1][v] + bb[1];
      const float zc = acc[r][2][v] + bb[2];
      const float zo = acc[r][3][v] + bb[3];
      const float ig = sigm(zi);
      const float fg = sigm(zf);
      const float og = sigm(zo);
      const float rc = fmaxf(zc, 0.f);
      const float cv = fg * c0_sh[mloc * CSTR + wcol] + ig * rc;
      const float hv = og * fmaxf(cv, 0.f);
      c0_sh[mloc * CSTR + wcol] = cv;
      t_sh[mloc * CSTR + wcol] = hv;
    }
  }
  __syncthreads();
#pragma unroll
  for (int it = 0; it < 4; ++it) {
    const int fi = it * 512 + tid;
    const int row = fi >> 5, c4 = fi & 31;
    const float4 hv4 = *reinterpret_cast<const float4*>(&t_sh[row * CSTR + c4 * 4]);
    *reinterpret_cast<float4*>(out_h + (size_t)(m0 + row) * NL + cg * FB_COLS + c4 * 4) = hv4;
    const float4 cv4 = *reinterpret_cast<const float4*>(&c0_sh[row * CSTR + c4 * 4]);
    *reinterpret_cast<float4*>(out_c + (size_t)(m0 + row) * NL + cg * FB_COLS + c4 * 4) = cv4;
  }
  if (w < 4) {
    f32x4 lacc = (f32x4){0.f, 0.f, 0.f, 0.f};
#pragma unroll
    for (int kk2 = 0; kk2 < 4; ++kk2) {
      const float4 hlo = *reinterpret_cast<const float4*>(&t_sh[(w * 16 + lrow) * CSTR + kk2 * 32 + lk8]);
      const float4 hhi = *reinterpret_cast<const float4*>(&t_sh[(w * 16 + lrow) * CSTR + kk2 * 32 + lk8 + 4]);
      bf16x8 ah;
      ah[0] = (__bf16)hlo.x; ah[1] = (__bf16)hlo.y;
      ah[2] = (__bf16)hlo.z; ah[3] = (__bf16)hlo.w;
      ah[4] = (__bf16)hhi.x; ah[5] = (__bf16)hhi.y;
      ah[6] = (__bf16)hhi.z; ah[7] = (__bf16)hhi.w;
      const bf16x8 bw = *reinterpret_cast<const bf16x8*>(&WdTg[lrow * 256 + cg * FB_COLS + kk2 * 32 + lk8]);
      lacc = __builtin_amdgcn_mfma_f32_16x16x32_bf16(ah, bw, lacc, 0, 0, 0);
    }
    if (lrow < FEAT) {
      const float addv = (cg == 0) ? bd[lrow] : 0.f;
#pragma unroll
      for (int v = 0; v < 4; ++v)
        atomicAdd(&out_logits[(size_t)(m0 + w * 16 + lq + v) * FEAT + lrow], lacc[v] + addv);
    }
  }
}

extern "C" void kernel_launch(void* const* d_in, const int* in_sizes, int n_in,
                              void* d_out, int out_size, void* d_ws, size_t ws_size,
                              hipStream_t stream) {
  const float* x = (const float*)d_in[0];
  const float* h0 = (const float*)d_in[1];
  const float* c0 = (const float*)d_in[2];
  const float* W = (const float*)d_in[3];
  const float* U = (const float*)d_in[4];
  const float* b = (const float*)d_in[5];
  const float* Wd = (const float*)d_in[6];
  const float* bd = (const float*)d_in[7];

  unsigned short* Ut = (unsigned short*)d_ws;            // 589824 B
  unsigned short* WdTg = Ut + (size_t)NZ * KTOT;         // +8192 B
  unsigned short* Abig = WdTg + 16 * 256;                // +37748736 B
  const size_t need = (size_t)NZ * KTOT * 2 + 16 * 256 * 2 + (size_t)BATCH * AST * 2;

  hipMemsetAsync(d_out, 0, (size_t)BATCH * FEAT * sizeof(float), stream);

  if (ws_size >= need) {
    k_prep_all<<<8592, 256, 0, stream>>>(h0, x, U, W, Wd, Abig, Ut, WdTg);
    k_lstm_p<<<NBLK, 512, 0, stream>>>(c0, b, bd, Ut, WdTg, Abig, (float*)d_out);
  } else {
    k_prep_fb<<<256, 256, 0, stream>>>(U, Ut);
    k_prepx_fb<<<32, 1024, 0, stream>>>(W, Wd, Ut, WdTg);
    k_lstm_fb<<<(BATCH / FB_ROWS) * 2, 512, 0, stream>>>(x, h0, c0, b, bd, Ut, WdTg,
                                                         (float*)d_out);
  }
}

// Round 20
// 95.564 us; speedup vs baseline: 2.4782x; 1.2367x over previous
//
#include <hip/hip_runtime.h>
#include <hip/hip_bf16.h>

typedef __bf16 bf16x8 __attribute__((ext_vector_type(8)));
typedef float f32x4 __attribute__((ext_vector_type(4)));
typedef unsigned int u32;

#define BATCH 65536
#define NL 256
#define NZ 1024
#define FEAT 5
#define KTOT 288   // 256 (h@U) + 32 (x@W folded)
#define AST 288    // Abig / A_sh row stride (bf16): 576B, raw-copyable
#define ROWS 32    // rows per tile
#define COLS 64    // gate-cols per block
#define SLAB_T 16  // tiles per persistent block
#define NBLK 512   // persistent blocks (2/CU)
#define TSTR 68    // t_sh row stride (f32)
// fallback (R13) constants
#define FB_ROWS 64
#define FB_COLS 128
#define ASTRIDE 296
#define CSTR 132

__device__ __forceinline__ unsigned short f2bf(float f) {
  __hip_bfloat16 h = __float2bfloat16(f);  // RTNE
  return __builtin_bit_cast(unsigned short, h);
}
__device__ __forceinline__ float sigm(float z) {
  return __builtin_amdgcn_rcpf(1.f + __builtin_amdgcn_exp2f(z * -1.4426950408889634f));
}

#define GLOAD16(g, l)                                                              \
  __builtin_amdgcn_global_load_lds((const __attribute__((address_space(1))) u32*)(g), \
                                   (__attribute__((address_space(3))) u32*)(l), 16, 0, 0)

// ---- merged prep: [0,8192) Abig | [8192,8448) U-transpose | [8448,8576) Ut-x | [8576,8592) WdTg
__global__ __launch_bounds__(256) void k_prep_all(
    const float* __restrict__ h0, const float* __restrict__ x,
    const float* __restrict__ U, const float* __restrict__ W,
    const float* __restrict__ Wd, unsigned short* __restrict__ Abig,
    unsigned short* __restrict__ Ut, unsigned short* __restrict__ WdTg) {
  __shared__ float t[32][33];
  const int tid = threadIdx.x;
  const int bid = blockIdx.x;

  if (bid < 8192) {  // Abig[row][0..255]=bf16(h0), [256..260]=bf16(x), [261..287]=0
    const int row8 = bid * 8;
    const int r = tid >> 5;
    const int c8 = tid & 31;
    const int row = row8 + r;
    const float4 v0 = *reinterpret_cast<const float4*>(h0 + (size_t)row * NL + c8 * 8);
    const float4 v1 = *reinterpret_cast<const float4*>(h0 + (size_t)row * NL + c8 * 8 + 4);
    unsigned short* dst = Abig + (size_t)row * AST + c8 * 8;
    *reinterpret_cast<ushort4*>(dst) = make_ushort4(f2bf(v0.x), f2bf(v0.y), f2bf(v0.z), f2bf(v0.w));
    *reinterpret_cast<ushort4*>(dst + 4) = make_ushort4(f2bf(v1.x), f2bf(v1.y), f2bf(v1.z), f2bf(v1.w));
    if (tid < 32) {
      const int rr = row8 + (tid >> 2);
      const int seg = tid & 3;
      unsigned short vals[8];
#pragma unroll
      for (int e = 0; e < 8; ++e) {
        const int col = seg * 8 + e;
        vals[e] = (col < FEAT) ? f2bf(x[(size_t)rr * FEAT + col]) : (unsigned short)0;
      }
      unsigned short* d2 = Abig + (size_t)rr * AST + 256 + seg * 8;
      *reinterpret_cast<ushort4*>(d2) = make_ushort4(vals[0], vals[1], vals[2], vals[3]);
      *reinterpret_cast<ushort4*>(d2 + 4) = make_ushort4(vals[4], vals[5], vals[6], vals[7]);
    }
  } else if (bid < 8448) {  // U [256][1024] -> Ut [1024][288] rows k=0..255
    const int b2 = bid - 8192;
    const int bk = b2 >> 5;
    const int bn = b2 & 31;
    const int r = tid >> 5;
    const int c = tid & 31;
#pragma unroll
    for (int i = 0; i < 4; ++i)
      t[r + 8 * i][c] = U[(size_t)(bk * 32 + r + 8 * i) * NZ + bn * 32 + c];
    __syncthreads();
#pragma unroll
    for (int i = 0; i < 4; ++i)
      Ut[(size_t)(bn * 32 + r + 8 * i) * KTOT + bk * 32 + c] = f2bf(t[c][r + 8 * i]);
  } else if (bid < 8576) {  // Ut k-rows 256..287 = [W(5); zeros]
    const int idx = (bid - 8448) * 256 + tid;  // 32768
    const int n = idx >> 5;
    const int cc = idx & 31;
    Ut[(size_t)n * KTOT + 256 + cc] =
        (cc < FEAT) ? f2bf(W[(size_t)cc * NZ + n]) : (unsigned short)0;
  } else {  // WdTg [16][256]
    const int idx = (bid - 8576) * 256 + tid;  // 4096
    const int p = idx >> 8;
    const int j = idx & 255;
    WdTg[p * 256 + j] = (p < FEAT) ? f2bf(Wd[(size_t)j * FEAT + p]) : (unsigned short)0;
  }
}

// async stage of tile: A (18 KB linear raw copy) + c0 slice (8 KB raw copy)
__device__ __forceinline__ void issue_tile(const unsigned short* Abig, const float* c0,
                                           int mt, int cg, int w, int l,
                                           unsigned short* Abuf, float* Cbuf) {
  const char* gA = (const char*)(Abig + (size_t)mt * AST);
  char* lA = (char*)Abuf;
#pragma unroll
  for (int i = 0; i < 5; ++i) {
    const int ii = w + i * 4;  // wave-uniform
    if (ii < 18) GLOAD16(gA + ii * 1024 + l * 16, lA + ii * 1024);
  }
  const char* gC = (const char*)c0;
  char* lC = (char*)Cbuf;
#pragma unroll
  for (int j = 0; j < 2; ++j) {
    const int jj = w + j * 4;
    const int rr = jj * 4 + (l >> 4);
    GLOAD16(gC + ((size_t)(mt + rr) * NL + cg * COLS) * 4 + (l & 15) * 16, lC + jj * 1024);
  }
}

// Persistent pipelined hot kernel: 512 blocks x 256 thr (2/CU), slab of 16 tiles,
// dbuf A+c0 via global_load_lds (zero reg cost), B reg-rotation (256-reg budget),
// counted vmcnt(8) tile drain (stores stay in flight across the barrier).
// FINAL: occupancy levers falsified (R12/R16/R18/R19); this is the design optimum.
__global__ __launch_bounds__(256, 2) void k_lstm_p(
    const float* __restrict__ c0, const float* __restrict__ b,
    const float* __restrict__ bd, const unsigned short* __restrict__ Ut,
    const unsigned short* __restrict__ WdTg,
    const unsigned short* __restrict__ Abig, float* __restrict__ out) {
  float* out_logits = out;
  float* out_h = out + (size_t)BATCH * FEAT;
  float* out_c = out_h + (size_t)BATCH * NL;

  __shared__ __align__(16) unsigned short A_sh[2][ROWS * AST];  // 2 x 18432 B
  __shared__ __align__(16) float C_sh[2][ROWS * COLS];          // 2 x 8192 B
  __shared__ __align__(16) float t_sh[ROWS * TSTR];             // 8704 B

  const int tid = threadIdx.x;
  const int w = tid >> 6;
  const int l = tid & 63;
  const int lrow = l & 15;
  const int lk8 = (l >> 4) * 8;
  const int lq = (l >> 4) * 4;

  // XCD-contiguous: 64 blocks/XCD = 16 slabs x 4 cg (cg-siblings co-XCD)
  const int xcd = (int)blockIdx.x & 7;
  const int gidx = xcd * 64 + ((int)blockIdx.x >> 3);  // 0..511
  const int cg = gidx & 3;
  const int slab = gidx >> 2;                          // 0..127
  const int mbase = slab * (ROWS * SLAB_T);

  const int jcol = cg * COLS + w * 16 + lrow;
  const int wcol = w * 16 + lrow;

  float bb[4];
#pragma unroll
  for (int g = 0; g < 4; ++g) bb[g] = b[g * 256 + jcol];
  const unsigned short* bp[4];
#pragma unroll
  for (int g = 0; g < 4; ++g) bp[g] = Ut + (size_t)(g * 256 + jcol) * KTOT + lk8;
  const float bdv = (cg == 0 && lrow < FEAT) ? bd[lrow] : 0.f;

  issue_tile(Abig, c0, mbase, cg, w, l, &A_sh[0][0], &C_sh[0][0]);
  asm volatile("s_waitcnt vmcnt(0)" ::: "memory");
  __syncthreads();

  int cur = 0;
#pragma unroll 1
  for (int t = 0; t < SLAB_T; ++t) {
    const int m0 = mbase + t * ROWS;
    if (t + 1 < SLAB_T)
      issue_tile(Abig, c0, m0 + ROWS, cg, w, l, &A_sh[cur ^ 1][0], &C_sh[cur ^ 1][0]);

    // ---- k-loop on A_sh[cur]: B reg-rotation (2-deep), setprio on MFMA
    f32x4 acc[2][4];
#pragma unroll
    for (int r = 0; r < 2; ++r)
#pragma unroll
      for (int g = 0; g < 4; ++g) acc[r][g] = (f32x4){0.f, 0.f, 0.f, 0.f};
    const unsigned short* Ab = &A_sh[cur][0];

    bf16x8 bbuf[3][4];
#pragma unroll
    for (int g = 0; g < 4; ++g) bbuf[0][g] = *reinterpret_cast<const bf16x8*>(bp[g]);
#pragma unroll
    for (int g = 0; g < 4; ++g) bbuf[1][g] = *reinterpret_cast<const bf16x8*>(bp[g] + 32);

#pragma unroll
    for (int kk = 0; kk < 9; ++kk) {
      if (kk < 7) {
#pragma unroll
        for (int g = 0; g < 4; ++g)
          bbuf[(kk + 2) % 3][g] = *reinterpret_cast<const bf16x8*>(bp[g] + (kk + 2) * 32);
        __builtin_amdgcn_sched_group_barrier(0x20, 4, 0);  // VMEM_READ x4 first
      }
      const bf16x8 af0 = *reinterpret_cast<const bf16x8*>(&Ab[lrow * AST + kk * 32 + lk8]);
      const bf16x8 af1 =
          *reinterpret_cast<const bf16x8*>(&Ab[(16 + lrow) * AST + kk * 32 + lk8]);
      __builtin_amdgcn_sched_group_barrier(0x100, 2, 0);   // DS_READ x2
      __builtin_amdgcn_s_setprio(1);
#pragma unroll
      for (int g = 0; g < 4; ++g) {
        acc[0][g] = __builtin_amdgcn_mfma_f32_16x16x32_bf16(af0, bbuf[kk % 3][g], acc[0][g], 0, 0, 0);
        acc[1][g] = __builtin_amdgcn_mfma_f32_16x16x32_bf16(af1, bbuf[kk % 3][g], acc[1][g], 0, 0, 0);
      }
      __builtin_amdgcn_s_setprio(0);
      __builtin_amdgcn_sched_group_barrier(0x8, 8, 0);     // MFMA x8
    }

    // ---- gates: c0 from LDS; c back to same slot; h -> t_sh
#pragma unroll
    for (int r = 0; r < 2; ++r) {
#pragma unroll
      for (int v = 0; v < 4; ++v) {
        const int mloc = r * 16 + lq + v;
        const float zi = acc[r][0][v] + bb[0];
        const float zf = acc[r][1][v] + bb[1];
        const float zc = acc[r][2][v] + bb[2];
        const float zo = acc[r][3][v] + bb[3];
        const float ig = sigm(zi);
        const float fg = sigm(zf);
        const float og = sigm(zo);
        const float rc = fmaxf(zc, 0.f);
        const float cv = fg * C_sh[cur][mloc * COLS + wcol] + ig * rc;
        const float hv = og * fmaxf(cv, 0.f);
        C_sh[cur][mloc * COLS + wcol] = cv;  // same-thread slot
        t_sh[mloc * TSTR + wcol] = hv;
      }
    }
    __syncthreads();  // B1

    // ---- coalesced h & c stores (2 float4/thread each), logits on waves 0,1
#pragma unroll
    for (int it = 0; it < 2; ++it) {
      const int fi = it * 256 + tid;  // 512 float4 = 32 rows x 16
      const int row = fi >> 4, c4 = fi & 15;
      const float4 hv4 = *reinterpret_cast<const float4*>(&t_sh[row * TSTR + c4 * 4]);
      *reinterpret_cast<float4*>(out_h + (size_t)(m0 + row) * NL + cg * COLS + c4 * 4) = hv4;
      const float4 cv4 = *reinterpret_cast<const float4*>(&C_sh[cur][row * COLS + c4 * 4]);
      *reinterpret_cast<float4*>(out_c + (size_t)(m0 + row) * NL + cg * COLS + c4 * 4) = cv4;
    }
    if (w < 2) {
      f32x4 lacc = (f32x4){0.f, 0.f, 0.f, 0.f};
#pragma unroll
      for (int kk2 = 0; kk2 < 2; ++kk2) {
        const float4 hlo = *reinterpret_cast<const float4*>(
            &t_sh[(w * 16 + lrow) * TSTR + kk2 * 32 + lk8]);
        const float4 hhi = *reinterpret_cast<const float4*>(
            &t_sh[(w * 16 + lrow) * TSTR + kk2 * 32 + lk8 + 4]);
        bf16x8 ah;
        ah[0] = (__bf16)hlo.x; ah[1] = (__bf16)hlo.y;
        ah[2] = (__bf16)hlo.z; ah[3] = (__bf16)hlo.w;
        ah[4] = (__bf16)hhi.x; ah[5] = (__bf16)hhi.y;
        ah[6] = (__bf16)hhi.z; ah[7] = (__bf16)hhi.w;
        const bf16x8 bw = *reinterpret_cast<const bf16x8*>(
            &WdTg[lrow * 256 + cg * COLS + kk2 * 32 + lk8]);
        lacc = __builtin_amdgcn_mfma_f32_16x16x32_bf16(ah, bw, lacc, 0, 0, 0);
      }
      if (lrow < FEAT) {
#pragma unroll
        for (int v = 0; v < 4; ++v)
          atomicAdd(&out_logits[(size_t)(m0 + w * 16 + lq + v) * FEAT + lrow],
                    lacc[v] + bdv);
      }
    }
    // counted drain: staging gloads provably retired once <=8 VM ops remain
    // (>=32 k-loop B loads + stores + atomics issued after them).
    asm volatile("s_waitcnt vmcnt(8)" ::: "memory");
    __syncthreads();  // B2
    cur ^= 1;
  }
}

// ---------------- fallback (ws too small): R13 kernel + split preps ----------------
__global__ __launch_bounds__(256) void k_prep_fb(const float* __restrict__ U,
                                                 unsigned short* __restrict__ Ut) {
  __shared__ float t[32][33];
  const int bk = blockIdx.x >> 5;
  const int bn = blockIdx.x & 31;
  const int r = threadIdx.x >> 5;
  const int c = threadIdx.x & 31;
#pragma unroll
  for (int i = 0; i < 4; ++i)
    t[r + 8 * i][c] = U[(size_t)(bk * 32 + r + 8 * i) * NZ + bn * 32 + c];
  __syncthreads();
#pragma unroll
  for (int i = 0; i < 4; ++i)
    Ut[(size_t)(bn * 32 + r + 8 * i) * KTOT + bk * 32 + c] = f2bf(t[c][r + 8 * i]);
}
__global__ __launch_bounds__(1024) void k_prepx_fb(const float* __restrict__ W,
                                                   const float* __restrict__ Wd,
                                                   unsigned short* __restrict__ Ut,
                                                   unsigned short* __restrict__ WdTg) {
  const int idx = blockIdx.x * 1024 + threadIdx.x;
  const int n = idx >> 5;
  const int cc = idx & 31;
  Ut[(size_t)n * KTOT + 256 + cc] = (cc < FEAT) ? f2bf(W[(size_t)cc * NZ + n]) : (unsigned short)0;
  if (blockIdx.x < 4) {
    const int p = idx >> 8;
    const int j = idx & 255;
    WdTg[p * 256 + j] = (p < FEAT) ? f2bf(Wd[(size_t)j * FEAT + p]) : (unsigned short)0;
  }
}
__global__ __launch_bounds__(512, 4) void k_lstm_fb(
    const float* __restrict__ x, const float* __restrict__ h0,
    const float* __restrict__ c0, const float* __restrict__ b,
    const float* __restrict__ bd, const unsigned short* __restrict__ Ut,
    const unsigned short* __restrict__ WdTg, float* __restrict__ out) {
  float* out_logits = out;
  float* out_h = out + (size_t)BATCH * FEAT;
  float* out_c = out_h + (size_t)BATCH * NL;
  __shared__ __align__(16) unsigned short A_sh[FB_ROWS * ASTRIDE];
  __shared__ __align__(16) float c0_sh[FB_ROWS * CSTR];
  const int tid = threadIdx.x;
  const int w = tid >> 6;
  const int l = tid & 63;
  const int lrow = l & 15;
  const int lk8 = (l >> 4) * 8;
  const int lq = (l >> 4) * 4;
  const int nb = ((int)blockIdx.x & 7) * 256 + ((int)blockIdx.x >> 3);
  const int cg = nb & 1;
  const int m0 = (nb >> 1) * FB_ROWS;
  const int jcol = cg * FB_COLS + w * 16 + lrow;
  const int wcol = w * 16 + lrow;
  {
    float4 sv[8];
#pragma unroll
    for (int it = 0; it < 8; ++it) {
      const int fi = it * 512 + tid;
      const int row = fi >> 6, c4 = fi & 63;
      sv[it] = *reinterpret_cast<const float4*>(h0 + (size_t)(m0 + row) * NL + c4 * 4);
    }
#pragma unroll
    for (int it = 0; it < 8; ++it) {
      const int fi = it * 512 + tid;
      const int row = fi >> 6, c4 = fi & 63;
      *reinterpret_cast<ushort4*>(&A_sh[row * ASTRIDE + c4 * 4]) =
          make_ushort4(f2bf(sv[it].x), f2bf(sv[it].y), f2bf(sv[it].z), f2bf(sv[it].w));
    }
  }
  {
    float4 cv[4];
#pragma unroll
    for (int it = 0; it < 4; ++it) {
      const int fi = it * 512 + tid;
      const int row = fi >> 5, c4 = fi & 31;
      cv[it] = *reinterpret_cast<const float4*>(c0 + (size_t)(m0 + row) * NL + cg * FB_COLS + c4 * 4);
    }
#pragma unroll
    for (int it = 0; it < 4; ++it) {
      const int fi = it * 512 + tid;
      const int row = fi >> 5, c4 = fi & 31;
      *reinterpret_cast<float4*>(&c0_sh[row * CSTR + c4 * 4]) = cv[it];
    }
  }
#pragma unroll
  for (int it = 0; it < 4; ++it) {
    const int idx = it * 512 + tid;
    const int row = idx >> 5, cc = idx & 31;
    const float xv = (cc < FEAT) ? x[(size_t)(m0 + row) * FEAT + cc] : 0.f;
    A_sh[row * ASTRIDE + 256 + cc] = f2bf(xv);
  }
  __syncthreads();
  float bb[4];
#pragma unroll
  for (int g = 0; g < 4; ++g) bb[g] = b[g * 256 + jcol];
  f32x4 acc[4][4];
#pragma unroll
  for (int r = 0; r < 4; ++r)
#pragma unroll
    for (int g = 0; g < 4; ++g) acc[r][g] = (f32x4){0.f, 0.f, 0.f, 0.f};
  const unsigned short* bp[4];
#pragma unroll
  for (int g = 0; g < 4; ++g) bp[g] = Ut + (size_t)(g * 256 + jcol) * KTOT + lk8;
#pragma unroll
  for (int kk = 0; kk < 9; ++kk) {
    bf16x8 bf[4];
#pragma unroll
    for (int g = 0; g < 4; ++g) bf[g] = *reinterpret_cast<const bf16x8*>(bp[g] + kk * 32);
    bf16x8 af[4];
#pragma unroll
    for (int r = 0; r < 4; ++r)
      af[r] = *reinterpret_cast<const bf16x8*>(&A_sh[(r * 16 + lrow) * ASTRIDE + kk * 32 + lk8]);
#pragma unroll
    for (int g = 0; g < 4; ++g)
#pragma unroll
      for (int r = 0; r < 4; ++r)
        acc[r][g] = __builtin_amdgcn_mfma_f32_16x16x32_bf16(af[r], bf[g], acc[r][g], 0, 0, 0);
  }
  __syncthreads();
  float* t_sh = reinterpret_cast<float*>(A_sh);
#pragma unroll
  for (int r = 0; r < 4; ++r) {
#pragma unroll
    for (int v = 0; v < 4; ++v) {
      const int mloc = r * 16 + lq + v;
      const float zi = acc[r][0][v] + bb[0];
      const float zf = acc[r][1][v] + bb[1];
      const float zc = acc[r][2][v] + bb[2];
      const float zo = acc[r][3][v] + bb[3];
      const float ig = sigm(zi);
      const float fg = sigm(zf);
      const float og = sigm(zo);
      const float rc = fmaxf(zc, 0.f);
      const float cv = fg * c0_sh[mloc * CSTR + wcol] + ig * rc;
      const float hv = og * fmaxf(cv, 0.f);
      c0_sh[mloc * CSTR + wcol] = cv;
      t_sh[mloc * CSTR + wcol] = hv;
    }
  }
  __syncthreads();
#pragma unroll
  for (int it = 0; it < 4; ++it) {
    const int fi = it * 512 + tid;
    const int row = fi >> 5, c4 = fi & 31;
    const float4 hv4 = *reinterpret_cast<const float4*>(&t_sh[row * CSTR + c4 * 4]);
    *reinterpret_cast<float4*>(out_h + (size_t)(m0 + row) * NL + cg * FB_COLS + c4 * 4) = hv4;
    const float4 cv4 = *reinterpret_cast<const float4*>(&c0_sh[row * CSTR + c4 * 4]);
    *reinterpret_cast<float4*>(out_c + (size_t)(m0 + row) * NL + cg * FB_COLS + c4 * 4) = cv4;
  }
  if (w < 4) {
    f32x4 lacc = (f32x4){0.f, 0.f, 0.f, 0.f};
#pragma unroll
    for (int kk2 = 0; kk2 < 4; ++kk2) {
      const float4 hlo = *reinterpret_cast<const float4*>(&t_sh[(w * 16 + lrow) * CSTR + kk2 * 32 + lk8]);
      const float4 hhi = *reinterpret_cast<const float4*>(&t_sh[(w * 16 + lrow) * CSTR + kk2 * 32 + lk8 + 4]);
      bf16x8 ah;
      ah[0] = (__bf16)hlo.x; ah[1] = (__bf16)hlo.y;
      ah[2] = (__bf16)hlo.z; ah[3] = (__bf16)hlo.w;
      ah[4] = (__bf16)hhi.x; ah[5] = (__bf16)hhi.y;
      ah[6] = (__bf16)hhi.z; ah[7] = (__bf16)hhi.w;
      const bf16x8 bw = *reinterpret_cast<const bf16x8*>(&WdTg[lrow * 256 + cg * FB_COLS + kk2 * 32 + lk8]);
      lacc = __builtin_amdgcn_mfma_f32_16x16x32_bf16(ah, bw, lacc, 0, 0, 0);
    }
    if (lrow < FEAT) {
      const float addv = (cg == 0) ? bd[lrow] : 0.f;
#pragma unroll
      for (int v = 0; v < 4; ++v)
        atomicAdd(&out_logits[(size_t)(m0 + w * 16 + lq + v) * FEAT + lrow], lacc[v] + addv);
    }
  }
}

extern "C" void kernel_launch(void* const* d_in, const int* in_sizes, int n_in,
                              void* d_out, int out_size, void* d_ws, size_t ws_size,
                              hipStream_t stream) {
  const float* x = (const float*)d_in[0];
  const float* h0 = (const float*)d_in[1];
  const float* c0 = (const float*)d_in[2];
  const float* W = (const float*)d_in[3];
  const float* U = (const float*)d_in[4];
  const float* b = (const float*)d_in[5];
  const float* Wd = (const float*)d_in[6];
  const float* bd = (const float*)d_in[7];

  unsigned short* Ut = (unsigned short*)d_ws;            // 589824 B
  unsigned short* WdTg = Ut + (size_t)NZ * KTOT;         // +8192 B
  unsigned short* Abig = WdTg + 16 * 256;                // +37748736 B
  const size_t need = (size_t)NZ * KTOT * 2 + 16 * 256 * 2 + (size_t)BATCH * AST * 2;

  hipMemsetAsync(d_out, 0, (size_t)BATCH * FEAT * sizeof(float), stream);

  if (ws_size >= need) {
    k_prep_all<<<8592, 256, 0, stream>>>(h0, x, U, W, Wd, Abig, Ut, WdTg);
    k_lstm_p<<<NBLK, 256, 0, stream>>>(c0, b, bd, Ut, WdTg, Abig, (float*)d_out);
  } else {
    k_prep_fb<<<256, 256, 0, stream>>>(U, Ut);
    k_prepx_fb<<<32, 1024, 0, stream>>>(W, Wd, Ut, WdTg);
    k_lstm_fb<<<(BATCH / FB_ROWS) * 2, 512, 0, stream>>>(x, h0, c0, b, bd, Ut, WdTg,
                                                         (float*)d_out);
  }
}